// Round 1
// baseline (300.047 us; speedup 1.0000x reference)
//
#include <hip/hip_runtime.h>
#include <math.h>

#define BB 16
#define NN 4096
#define DD 128
#define KK 1024
#define NPTS (BB*NN)

// ---------------- kernel 0: centroid squared norms (double accum) ----------------
__global__ void cnorm_kernel(const float* __restrict__ c, float* __restrict__ cnorm) {
    int k = blockIdx.x * 256 + threadIdx.x;
    if (k >= KK) return;
    const float* row = c + k * DD;
    double s = 0.0;
#pragma unroll
    for (int d = 0; d < DD; ++d) { double v = (double)row[d]; s += v * v; }
    cnorm[k] = (float)s;
}

// ---------------- kernel 1: nearest-centroid assignment ----------------
// Block: 256 threads = 16(tx: centroid groups) x 16(ty: point groups)
// Block tile: 64 points x (all 1024 centroids, in 16 tiles of 64)
// Per-thread: 4 points x 4 centroids fp32 accumulators.
// LDS float4 tiles XOR-swizzled on the float4-block index keyed by (row>>2)&7
// -> conflict-free ds_read_b128 for both x (key=ty) and c (key=tx, 2-way=free).
__launch_bounds__(256, 2)
__global__ void assign_kernel(const float* __restrict__ x, const float* __restrict__ cent,
                              const float* __restrict__ cnorm,
                              float* __restrict__ min_d, int* __restrict__ nearest) {
    __shared__ float4 xs4[64 * 32];
    __shared__ float4 cs4[64 * 32];
    __shared__ float cnS[KK];
    __shared__ float rbest[64][17];
    __shared__ int   rbestk[64][17];

    const int tid = threadIdx.x;
    const int tx = tid & 15;
    const int ty = tid >> 4;
    const int p0 = blockIdx.x * 64;

    // stage x tile (swizzled) once; stage cnorm
    const float4* xsrc = (const float4*)(x) + (size_t)p0 * 32;
#pragma unroll
    for (int j = 0; j < 8; ++j) {
        int i = tid + 256 * j;
        int r = i >> 5, d4 = i & 31;
        xs4[r * 32 + (d4 ^ ((r >> 2) & 7))] = xsrc[i];
    }
#pragma unroll
    for (int j = 0; j < 4; ++j) cnS[tid + 256 * j] = cnorm[tid + 256 * j];

    float best[4];
    int bestk[4];
#pragma unroll
    for (int pi = 0; pi < 4; ++pi) { best[pi] = INFINITY; bestk[pi] = 0; }

    const int sx = ty & 7;
    const int sc = tx & 7;

    for (int kt = 0; kt < 16; ++kt) {
        const int k0 = kt * 64;
        __syncthreads();  // cs4 from previous tile no longer needed
        const float4* csrc = (const float4*)(cent) + (size_t)k0 * 32;
#pragma unroll
        for (int j = 0; j < 8; ++j) {
            int i = tid + 256 * j;
            int r = i >> 5, d4 = i & 31;
            cs4[r * 32 + (d4 ^ ((r >> 2) & 7))] = csrc[i];
        }
        __syncthreads();

        float acc[4][4];
#pragma unroll
        for (int a = 0; a < 4; ++a)
#pragma unroll
            for (int b = 0; b < 4; ++b) acc[a][b] = 0.f;

#pragma unroll 8
        for (int d4 = 0; d4 < 32; ++d4) {
            float4 xv[4], cv[4];
#pragma unroll
            for (int pi = 0; pi < 4; ++pi) xv[pi] = xs4[(ty * 4 + pi) * 32 + (d4 ^ sx)];
#pragma unroll
            for (int kj = 0; kj < 4; ++kj) cv[kj] = cs4[(tx * 4 + kj) * 32 + (d4 ^ sc)];
#pragma unroll
            for (int pi = 0; pi < 4; ++pi)
#pragma unroll
                for (int kj = 0; kj < 4; ++kj) {
                    acc[pi][kj] = fmaf(xv[pi].x, cv[kj].x, acc[pi][kj]);
                    acc[pi][kj] = fmaf(xv[pi].y, cv[kj].y, acc[pi][kj]);
                    acc[pi][kj] = fmaf(xv[pi].z, cv[kj].z, acc[pi][kj]);
                    acc[pi][kj] = fmaf(xv[pi].w, cv[kj].w, acc[pi][kj]);
                }
        }

#pragma unroll
        for (int pi = 0; pi < 4; ++pi)
#pragma unroll
            for (int kj = 0; kj < 4; ++kj) {
                int k = k0 + tx * 4 + kj;
                float val = cnS[k] - 2.0f * acc[pi][kj];
                if (val < best[pi]) { best[pi] = val; bestk[pi] = k; }  // strict <: first-min wins (k ascending in-thread)
            }
    }

    // cross-thread (over tx) argmin reduction, numpy tie-break: smaller k
#pragma unroll
    for (int pi = 0; pi < 4; ++pi) {
        rbest[ty * 4 + pi][tx] = best[pi];
        rbestk[ty * 4 + pi][tx] = bestk[pi];
    }
    __syncthreads();
    if (tid < 64) {
        const int p = tid;
        float bv = rbest[p][0];
        int bk = rbestk[p][0];
#pragma unroll
        for (int t = 1; t < 16; ++t) {
            float v = rbest[p][t];
            int k = rbestk[p][t];
            if (v < bv || (v == bv && k < bk)) { bv = v; bk = k; }
        }
        // ||x||^2 in double (bias-free; only shifts min_d, not argmin)
        double xn = 0.0;
#pragma unroll
        for (int d4 = 0; d4 < 32; ++d4) {
            float4 v = xs4[p * 32 + (d4 ^ ((p >> 2) & 7))];
            xn += (double)v.x * v.x + (double)v.y * v.y + (double)v.z * v.z + (double)v.w * v.w;
        }
        float sq = (float)xn + bv;
        min_d[p0 + p] = sqrtf(fmaxf(sq, 0.f));
        nearest[p0 + p] = bk;
    }
}

// ---------------- kernel 2: per-batch stats + histogram + normalize ----------------
__global__ void finalize_kernel(const float* __restrict__ min_d, const int* __restrict__ nearest,
                                const float* __restrict__ weights, float* __restrict__ out) {
    __shared__ float red[256];
    __shared__ int hist[KK];
    __shared__ float bc[2];  // mean, thr
    const int b = blockIdx.x;
    const int tid = threadIdx.x;
    const float* md = min_d + (size_t)b * NN;
    const int* nr = nearest + (size_t)b * NN;

    // pass A: mean (two-pass std to match numpy's numerics)
    float s = 0.f;
#pragma unroll
    for (int j = 0; j < NN / 256; ++j) s += md[tid + 256 * j];
    red[tid] = s;
    __syncthreads();
    for (int off = 128; off > 0; off >>= 1) {
        if (tid < off) red[tid] += red[tid + off];
        __syncthreads();
    }
    if (tid == 0) bc[0] = red[0] / (float)NN;
    __syncthreads();
    const float mean = bc[0];

    // pass B: sum of squared deviations -> thr = mean + std(ddof=1)
    float ss = 0.f;
#pragma unroll
    for (int j = 0; j < NN / 256; ++j) {
        float v = md[tid + 256 * j] - mean;
        ss += v * v;
    }
    red[tid] = ss;
    __syncthreads();
    for (int off = 128; off > 0; off >>= 1) {
        if (tid < off) red[tid] += red[tid + off];
        __syncthreads();
    }
    if (tid == 0) bc[1] = mean + sqrtf(red[0] / (float)(NN - 1));

    // histogram of masked assignments
    for (int j = tid; j < KK; j += 256) hist[j] = 0;
    __syncthreads();
    const float thr = bc[1];
#pragma unroll
    for (int j = 0; j < NN / 256; ++j) {
        int i = tid + 256 * j;
        if (md[i] < thr) atomicAdd(&hist[nr[i]], 1);
    }
    __syncthreads();

    // asmk = counts*weights; L2-normalize the row
    float a[4];
    float sq = 0.f;
#pragma unroll
    for (int t = 0; t < 4; ++t) {
        int k = tid * 4 + t;
        a[t] = (float)hist[k] * weights[k];
        sq += a[t] * a[t];
    }
    red[tid] = sq;
    __syncthreads();
    for (int off = 128; off > 0; off >>= 1) {
        if (tid < off) red[tid] += red[tid + off];
        __syncthreads();
    }
    const float norm = sqrtf(red[0]);
    const float scale = 1.f / fmaxf(norm, 1e-12f);
#pragma unroll
    for (int t = 0; t < 4; ++t) {
        int k = tid * 4 + t;
        out[(size_t)b * KK + k] = a[t] * scale;
    }
}

extern "C" void kernel_launch(void* const* d_in, const int* in_sizes, int n_in,
                              void* d_out, int out_size, void* d_ws, size_t ws_size,
                              hipStream_t stream) {
    const float* x = (const float*)d_in[0];
    const float* cent = (const float*)d_in[1];
    const float* weights = (const float*)d_in[2];
    float* out = (float*)d_out;

    float* min_d = (float*)d_ws;
    int* nearest = (int*)((char*)d_ws + (size_t)NPTS * 4);
    float* cnorm = (float*)((char*)d_ws + (size_t)NPTS * 8);

    cnorm_kernel<<<KK / 256, 256, 0, stream>>>(cent, cnorm);
    assign_kernel<<<NPTS / 64, 256, 0, stream>>>(x, cent, cnorm, min_d, nearest);
    finalize_kernel<<<BB, 256, 0, stream>>>(min_d, nearest, weights, out);
}